// Round 3
// baseline (249.423 us; speedup 1.0000x reference)
//
#include <hip/hip_runtime.h>

#define SLOPE 0.1f
#define EPS 1e-5f

typedef __bf16 bf16x8 __attribute__((ext_vector_type(8)));
typedef unsigned short u16x8 __attribute__((ext_vector_type(8)));
typedef float f32x4 __attribute__((ext_vector_type(4)));

// ---- workspace layout (float offsets; total 410816 floats = 1.64 MB) ----
#define WS_ESUM 0       // 32  edge col sums (zeroed by k1 blk 0)
#define WS_ESQ 32       // 32  edge col sumsq
#define WS_NSCALE 64    // 64
#define WS_NSHIFT 128   // 64
#define WS_A 192        // 512 : dot(xn_i, ev[0:64])
#define WS_B 704        // 512 : dot(xn_j, ev[96:160])
#define WS_XN 1216      // 512*64 post-lrelu node feats
#define WS_NEWX 33984   // 512*64 pre-BN new_x
#define WS_P1B 66752    // 512*80 : b_h2[k] + x_i . W_h2[k][0:64]
#define WS_P2 107712    // 512*80 : x_j . W_h2[k][96:160]
#define WS_SC 148672    // 512*512 scores (post-lrelu, pre-softmax)

__device__ __forceinline__ float lrelu(float v) { return v > 0.f ? v : SLOPE * v; }
__device__ __forceinline__ unsigned short f2bf(float f) {
  unsigned x = __float_as_uint(f);
  return (unsigned short)((x + 0x7fffu + ((x >> 16) & 1u)) >> 16);
}

// ---------------- K1: xn + a/b scalars + P1/P2 node projections ----------------
__global__ void __launch_bounds__(256) k1(const float* __restrict__ x,
                                          const float* __restrict__ W_nu,
                                          const float* __restrict__ b_nu,
                                          const float* __restrict__ W_h2,
                                          const float* __restrict__ b_h2,
                                          const float* __restrict__ ev,
                                          float* ws) {
  int blk = blockIdx.x;
  int tid = threadIdx.x;
  if (blk < 128) {
    if (blk == 0 && tid < 64) ws[WS_ESUM + tid] = 0.f;  // ESUM+ESQ adjacent
    // one wave per node row: xn[i][c], then wave-reduce a_i, b_i
    int i = blk * 4 + (tid >> 6);
    int c = tid & 63;
    float acc = b_nu[c];
    const float* xr = x + i * 64;
    const float* wr = W_nu + c * 64;
#pragma unroll 8
    for (int k = 0; k < 64; k++) acc += xr[k] * wr[k];
    float xnv = lrelu(acc);
    ws[WS_XN + i * 64 + c] = xnv;
    float va = xnv * ev[c];
    float vb = xnv * ev[96 + c];
#pragma unroll
    for (int off = 32; off >= 1; off >>= 1) {
      va += __shfl_xor(va, off, 64);
      vb += __shfl_xor(vb, off, 64);
    }
    if (c == 0) { ws[WS_A + i] = va; ws[WS_B + i] = vb; }
  } else {
    // thread per (p, i, k): P1 (p=0, W_h2 cols 0..63, +b_h2) / P2 (p=1, cols 96..159)
    int gid = (blk - 128) * 256 + tid;  // 0 .. 81919
    int p = gid / 40960;
    int r = gid - p * 40960;
    int i = r / 80;
    int k = r - i * 80;
    float acc = p ? 0.f : b_h2[k];
    const float* xr = x + i * 64;
    const float* wr = W_h2 + k * 160 + (p ? 96 : 0);
#pragma unroll 8
    for (int c = 0; c < 64; c++) acc += xr[c] * wr[c];
    ws[(p ? WS_P2 : WS_P1B) + i * 80 + k] = acc;
  }
}

// ---------------- K2: fused edge MLP (MFMA) + scores + BN-stat accumulation ----------------
// block = 64 edges (one i, 64 consecutive j), 4 waves x 16 edges each
__global__ void __launch_bounds__(256) k2(const float* __restrict__ ea,
                                          const int* __restrict__ mask,
                                          const float* __restrict__ W_h2,
                                          const float* __restrict__ W_eo,
                                          const float* __restrict__ b_eo,
                                          const float* __restrict__ ev,
                                          float* ws,
                                          float* __restrict__ out_e) {
  __shared__ float ht[64][97];      // h tile (fp32)
  __shared__ float wred[2][4][32];  // [sum|sumsq][wave][col]
  int tid = threadIdx.x;
  int wave = tid >> 6, lane = tid & 63;
  int c16 = lane & 15, q = lane >> 4;
  int blk = blockIdx.x;
  int i = blk >> 3, j0 = (blk & 7) << 6;

  // GEMM1 B-frags: B[n=k_out][k=c] = bf16(W_h2[n][64+c])
  bf16x8 wb[5];
#pragma unroll
  for (int t = 0; t < 5; t++) {
    int n = t * 16 + c16;
    const float* src = W_h2 + n * 160 + 64 + q * 8;
    u16x8 u;
#pragma unroll
    for (int jj = 0; jj < 8; jj++) u[jj] = f2bf(src[jj]);
    wb[t] = __builtin_bit_cast(bf16x8, u);
  }
  // GEMM1 A-frag: A[m=edge][k=c] = bf16(edge_attr)
  int mA = i * 512 + j0 + wave * 16 + c16;
  bf16x8 af;
  {
    const float* src = ea + mA * 32 + q * 8;
    u16x8 u;
#pragma unroll
    for (int jj = 0; jj < 8; jj++) u[jj] = f2bf(src[jj]);
    af = __builtin_bit_cast(bf16x8, u);
  }

  // acc init = P1b[i][k_out] + P2[j][k_out]  (rows = edges q*4+r, col = t*16+c16)
  f32x4 acc[5];
#pragma unroll
  for (int t = 0; t < 5; t++) {
    int n = t * 16 + c16;
    float p1v = ws[WS_P1B + i * 80 + n];
#pragma unroll
    for (int r = 0; r < 4; r++) {
      int j = j0 + wave * 16 + q * 4 + r;
      acc[t][r] = p1v + ws[WS_P2 + j * 80 + n];
    }
  }
#pragma unroll
  for (int t = 0; t < 5; t++)
    acc[t] = __builtin_amdgcn_mfma_f32_16x16x32_bf16(af, wb[t], acc[t], 0, 0, 0);

  // lrelu -> ht
#pragma unroll
  for (int t = 0; t < 5; t++)
#pragma unroll
    for (int r = 0; r < 4; r++)
      ht[wave * 16 + q * 4 + r][t * 16 + c16] = lrelu(acc[t][r]);

  __syncthreads();

  // GEMM2 B-frags: B[n=c_out][k] = bf16(W_eo[c_out][k]), zero-padded past k=80
  bf16x8 wo[2][3];
#pragma unroll
  for (int t2 = 0; t2 < 2; t2++)
#pragma unroll
    for (int s = 0; s < 3; s++) {
      int kk = s * 32 + q * 8;
      u16x8 u = {0, 0, 0, 0, 0, 0, 0, 0};
      if (kk < 80) {
        const float* src = W_eo + (t2 * 16 + c16) * 80 + kk;
#pragma unroll
        for (int jj = 0; jj < 8; jj++) u[jj] = f2bf(src[jj]);
      }
      wo[t2][s] = __builtin_bit_cast(bf16x8, u);
    }

  // GEMM2: ne = h @ W_eo^T (A re-read from ht in A-operand layout, cvt bf16)
  f32x4 z4 = {0.f, 0.f, 0.f, 0.f};
  f32x4 acc2[2] = {z4, z4};
  int hrow = wave * 16 + c16;
#pragma unroll
  for (int s = 0; s < 3; s++) {
    u16x8 hbits = {0, 0, 0, 0, 0, 0, 0, 0};
    int kk = s * 32 + q * 8;
    if (kk < 80) {
#pragma unroll
      for (int jj = 0; jj < 8; jj++) hbits[jj] = f2bf(ht[hrow][kk + jj]);
    }
    bf16x8 ha = __builtin_bit_cast(bf16x8, hbits);
#pragma unroll
    for (int t2 = 0; t2 < 2; t2++)
      acc2[t2] = __builtin_amdgcn_mfma_f32_16x16x32_bf16(ha, wo[t2][s], acc2[t2], 0, 0, 0);
  }

  // epilogue: bias, lrelu, mask; store fp32; col stats; score contributions
  float beo[2] = {b_eo[c16], b_eo[16 + c16]};
  float eve[2] = {ev[64 + c16], ev[80 + c16]};
  float ne[2][4];
  float scs[2] = {0.f, 0.f}, scss[2] = {0.f, 0.f};
#pragma unroll
  for (int t2 = 0; t2 < 2; t2++)
#pragma unroll
    for (int r = 0; r < 4; r++) {
      int m = i * 512 + j0 + wave * 16 + q * 4 + r;
      float mf = mask[m] ? 1.f : 0.f;
      float v = lrelu(acc2[t2][r] + beo[t2]) * mf;
      ne[t2][r] = v;
      scs[t2] += v;
      scss[t2] += v * v;
      out_e[m * 32 + t2 * 16 + c16] = v;
    }
  // per-wave column stats: reduce over q (lane bits 4,5)
#pragma unroll
  for (int t2 = 0; t2 < 2; t2++) {
    float a_ = scs[t2], b_ = scss[t2];
    a_ += __shfl_xor(a_, 16, 64); a_ += __shfl_xor(a_, 32, 64);
    b_ += __shfl_xor(b_, 16, 64); b_ += __shfl_xor(b_, 32, 64);
    if (q == 0) {
      wred[0][wave][t2 * 16 + c16] = a_;
      wred[1][wave][t2 * 16 + c16] = b_;
    }
  }
  // scores: se[r] = dot(ne[row], ev_mid), reduced over c16 (lane bits 0..3)
  float se[4];
#pragma unroll
  for (int r = 0; r < 4; r++) {
    float s = ne[0][r] * eve[0] + ne[1][r] * eve[1];
#pragma unroll
    for (int off = 8; off >= 1; off >>= 1) s += __shfl_xor(s, off, 64);
    se[r] = s;
  }
  if (c16 < 4) {
    float s = (c16 == 0) ? se[0] : (c16 == 1) ? se[1] : (c16 == 2) ? se[2] : se[3];
    int j = j0 + wave * 16 + q * 4 + c16;
    ws[WS_SC + i * 512 + j] = lrelu(ws[WS_A + i] + ws[WS_B + j] + s);
  }
  __syncthreads();
  if (tid < 32)
    atomicAdd(&ws[WS_ESUM + tid],
              wred[0][0][tid] + wred[0][1][tid] + wred[0][2][tid] + wred[0][3][tid]);
  else if (tid < 64)
    atomicAdd(&ws[WS_ESQ + tid - 32],
              wred[1][0][tid - 32] + wred[1][1][tid - 32] + wred[1][2][tid - 32] +
                  wred[1][3][tid - 32]);
}

// ---------------- K3: row softmax + mask + att@xn (pre-BN new_x) ----------------
__global__ void __launch_bounds__(256) k3(const int* __restrict__ mask, float* ws) {
  __shared__ float att[512];
  __shared__ float red1[4], red2[4];
  __shared__ float nx[4][64];
  int i = blockIdx.x, tid = threadIdx.x;
  int wave = tid >> 6, lane = tid & 63;
  const float* sc = ws + WS_SC + i * 512;
  float s0 = sc[tid], s1 = sc[tid + 256];
  float mx = fmaxf(s0, s1);
#pragma unroll
  for (int off = 32; off >= 1; off >>= 1) mx = fmaxf(mx, __shfl_xor(mx, off, 64));
  if (lane == 0) red1[wave] = mx;
  __syncthreads();
  mx = fmaxf(fmaxf(red1[0], red1[1]), fmaxf(red1[2], red1[3]));
  float p0 = __expf(s0 - mx), p1 = __expf(s1 - mx);
  float sm = p0 + p1;
#pragma unroll
  for (int off = 32; off >= 1; off >>= 1) sm += __shfl_xor(sm, off, 64);
  if (lane == 0) red2[wave] = sm;
  __syncthreads();
  sm = red2[0] + red2[1] + red2[2] + red2[3];
  float inv = 1.f / sm;
  att[tid] = p0 * inv * (mask[i * 512 + tid] ? 1.f : 0.f);
  att[tid + 256] = p1 * inv * (mask[i * 512 + tid + 256] ? 1.f : 0.f);
  __syncthreads();
  // new_x[i][c] = sum_j att[j] * xn[j][c]; wave w covers j in [w*128, (w+1)*128)
  int c = lane;
  const float* xn = ws + WS_XN;
  float accv = 0.f;
#pragma unroll 4
  for (int u = 0; u < 128; u++) {
    int j = wave * 128 + u;
    accv += att[j] * xn[j * 64 + c];
  }
  nx[wave][c] = accv;
  __syncthreads();
  if (tid < 64)
    ws[WS_NEWX + i * 64 + tid] = nx[0][tid] + nx[1][tid] + nx[2][tid] + nx[3][tid];
}

// ---------------- K4: BN stats for new_x (single block) ----------------
__global__ void __launch_bounds__(256) k4(const float* __restrict__ bn_n_w,
                                          const float* __restrict__ bn_n_b,
                                          float* ws) {
  __shared__ float s1[4][64], s2[4][64];
  int tid = threadIdx.x;
  int c = tid & 63, rg = tid >> 6;
  float a = 0.f, b = 0.f;
#pragma unroll 4
  for (int u = 0; u < 128; u++) {
    float v = ws[WS_NEWX + (rg * 128 + u) * 64 + c];
    a += v;
    b += v * v;
  }
  s1[rg][c] = a;
  s2[rg][c] = b;
  __syncthreads();
  if (tid < 64) {
    float sum = s1[0][tid] + s1[1][tid] + s1[2][tid] + s1[3][tid];
    float ssq = s2[0][tid] + s2[1][tid] + s2[2][tid] + s2[3][tid];
    float mean = sum * (1.f / 512.f);
    float var = ssq * (1.f / 512.f) - mean * mean;
    float scl = bn_n_w[tid] * rsqrtf(fmaxf(var, 0.f) + EPS);
    ws[WS_NSCALE + tid] = scl;
    ws[WS_NSHIFT + tid] = bn_n_b[tid] - mean * scl;
  }
}

// ---------------- K5: apply BN to new_x (blocks 0..7) and edges (blocks 8..4103) ----------------
__global__ void __launch_bounds__(256) k5(const float* __restrict__ bn_e_w,
                                          const float* __restrict__ bn_e_b,
                                          const float* __restrict__ ws,
                                          float* __restrict__ out) {
  __shared__ float esc[32], esh[32];
  int blk = blockIdx.x, tid = threadIdx.x;
  if (blk < 8) {
#pragma unroll 4
    for (int u = 0; u < 16; u++) {
      int idx = blk * 4096 + u * 256 + tid;
      int c = idx & 63;
      out[idx] = ws[WS_NEWX + idx] * ws[WS_NSCALE + c] + ws[WS_NSHIFT + c];
    }
  } else {
    if (tid < 32) {
      float mean = ws[WS_ESUM + tid] * (1.f / 262144.f);
      float var = ws[WS_ESQ + tid] * (1.f / 262144.f) - mean * mean;
      float s = bn_e_w[tid] * rsqrtf(fmaxf(var, 0.f) + EPS);
      esc[tid] = s;
      esh[tid] = bn_e_b[tid] - mean * s;
    }
    __syncthreads();
    float* oe = out + 32768;
    int base = ((blk - 8) * 256 + tid) * 8;  // 8 floats per thread, 32B aligned
    f32x4 r0 = *(const f32x4*)(oe + base);
    f32x4 r1 = *(const f32x4*)(oe + base + 4);
    int c0 = base & 31;
    f32x4 w0, w1;
#pragma unroll
    for (int u = 0; u < 4; u++) {
      w0[u] = r0[u] * esc[c0 + u] + esh[c0 + u];
      w1[u] = r1[u] * esc[c0 + 4 + u] + esh[c0 + 4 + u];
    }
    *(f32x4*)(oe + base) = w0;
    *(f32x4*)(oe + base + 4) = w1;
  }
}

extern "C" void kernel_launch(void* const* d_in, const int* in_sizes, int n_in,
                              void* d_out, int out_size, void* d_ws, size_t ws_size,
                              hipStream_t stream) {
  const float* x = (const float*)d_in[0];
  const float* ea = (const float*)d_in[1];
  const int* mask = (const int*)d_in[2];
  const float* Wnu = (const float*)d_in[3];
  const float* bnu = (const float*)d_in[4];
  const float* Wh2 = (const float*)d_in[5];
  const float* bh2 = (const float*)d_in[6];
  const float* Weo = (const float*)d_in[7];
  const float* beo = (const float*)d_in[8];
  const float* ev = (const float*)d_in[9];
  const float* bnw = (const float*)d_in[10];
  const float* bnb = (const float*)d_in[11];
  const float* bew = (const float*)d_in[12];
  const float* beb = (const float*)d_in[13];
  float* ws = (float*)d_ws;
  float* out = (float*)d_out;

  k1<<<448, 256, 0, stream>>>(x, Wnu, bnu, Wh2, bh2, ev, ws);
  k2<<<4096, 256, 0, stream>>>(ea, mask, Wh2, Weo, beo, ev, ws, out + 32768);
  k3<<<512, 256, 0, stream>>>(mask, ws);
  k4<<<1, 256, 0, stream>>>(bnw, bnb, ws);
  k5<<<4104, 256, 0, stream>>>(bew, beb, ws, out);
}

// Round 4
// 198.422 us; speedup vs baseline: 1.2570x; 1.2570x over previous
//
#include <hip/hip_runtime.h>

#define SLOPE 0.1f
#define EPS 1e-5f

typedef __bf16 bf16x8 __attribute__((ext_vector_type(8)));
typedef unsigned short u16x8 __attribute__((ext_vector_type(8)));
typedef float f32x4 __attribute__((ext_vector_type(4)));

// ---- workspace layout (float offsets; total 410816 floats = 1.64 MB) ----
#define WS_ESUM 0       // 32  edge col sums   (written by k4 blk1)
#define WS_ESQ 32       // 32  edge col sumsq  (written by k4 blk1)
#define WS_NSCALE 64    // 64
#define WS_NSHIFT 128   // 64
#define WS_A 192        // 512 : dot(xn_i, ev[0:64])
#define WS_B 704        // 512 : dot(xn_j, ev[96:160])
#define WS_XN 1216      // 512*64 post-lrelu node feats
#define WS_NEWX 33984   // 512*64 pre-BN new_x
#define WS_P1B 66752    // 512*80 : b_h2[k] + x_i . W_h2[k][0:64]
#define WS_P2 107712    // 512*80 : x_j . W_h2[k][96:160]
#define WS_SC 148672    // 512*512 scores (post-lrelu, pre-softmax)
// edge-BN partial stats (512 slots x 64 f32) live in d_out[0:32768] (x-region,
// dead until k5) -- zeroed by in-stream memset, consumed by k4 blk1.

__device__ __forceinline__ float lrelu(float v) { return v > 0.f ? v : SLOPE * v; }
__device__ __forceinline__ unsigned short f2bf(float f) {
  unsigned x = __float_as_uint(f);
  return (unsigned short)((x + 0x7fffu + ((x >> 16) & 1u)) >> 16);
}
__device__ __forceinline__ float bf2f(unsigned short u) {
  return __uint_as_float(((unsigned)u) << 16);
}

// ---------------- K1: xn + a/b scalars + P1/P2 node projections ----------------
__global__ void __launch_bounds__(256) k1(const float* __restrict__ x,
                                          const float* __restrict__ W_nu,
                                          const float* __restrict__ b_nu,
                                          const float* __restrict__ W_h2,
                                          const float* __restrict__ b_h2,
                                          const float* __restrict__ ev,
                                          float* ws) {
  int blk = blockIdx.x;
  int tid = threadIdx.x;
  if (blk < 128) {
    // one wave per node row: xn[i][c], then wave-reduce a_i, b_i
    int i = blk * 4 + (tid >> 6);
    int c = tid & 63;
    float acc = b_nu[c];
    const float* xr = x + i * 64;
    const float* wr = W_nu + c * 64;
#pragma unroll 8
    for (int k = 0; k < 64; k++) acc += xr[k] * wr[k];
    float xnv = lrelu(acc);
    ws[WS_XN + i * 64 + c] = xnv;
    float va = xnv * ev[c];
    float vb = xnv * ev[96 + c];
#pragma unroll
    for (int off = 32; off >= 1; off >>= 1) {
      va += __shfl_xor(va, off, 64);
      vb += __shfl_xor(vb, off, 64);
    }
    if (c == 0) { ws[WS_A + i] = va; ws[WS_B + i] = vb; }
  } else {
    // thread per (p, i, k): P1 (p=0, W_h2 cols 0..63, +b_h2) / P2 (p=1, cols 96..159)
    int gid = (blk - 128) * 256 + tid;  // 0 .. 81919
    int p = gid / 40960;
    int r = gid - p * 40960;
    int i = r / 80;
    int k = r - i * 80;
    float acc = p ? 0.f : b_h2[k];
    const float* xr = x + i * 64;
    const float* wr = W_h2 + k * 160 + (p ? 96 : 0);
#pragma unroll 8
    for (int c = 0; c < 64; c++) acc += xr[c] * wr[c];
    ws[(p ? WS_P2 : WS_P1B) + i * 80 + k] = acc;
  }
}

// ---------------- K2: fused edge MLP (MFMA) + scores + BN-stat partials ----------------
// block = 64 edges (one i, 64 consecutive j), 4 waves x 16 edges each
__global__ void __launch_bounds__(256) k2(const float* __restrict__ ea,
                                          const int* __restrict__ mask,
                                          const float* __restrict__ W_h2,
                                          const float* __restrict__ W_eo,
                                          const float* __restrict__ b_eo,
                                          const float* __restrict__ ev,
                                          float* ws,
                                          float* __restrict__ part,     // 512 slots x 64 f32
                                          float* __restrict__ out_e) {
  __shared__ unsigned short ht[64 * 104];   // h tile bf16, stride 104 (16B-aligned rows)
  __shared__ unsigned short p2s[64 * 82];   // P2 j-tile bf16, stride 82 (bank-spread)
  __shared__ float p1s[80];
  __shared__ float wred[2][4][32];          // [sum|sumsq][wave][col]
  int tid = threadIdx.x;
  int wave = tid >> 6, lane = tid & 63;
  int c16 = lane & 15, q = lane >> 4;
  int blk = blockIdx.x;
  int i = blk >> 3, j0 = (blk & 7) << 6;

  // --- stage P1 row + P2 tile into LDS (coalesced) ---
  if (tid < 80) p1s[tid] = ws[WS_P1B + i * 80 + tid];
#pragma unroll
  for (int it = 0; it < 20; it++) {
    int idx = it * 256 + tid;  // 0..5119 over the 64x80 tile
    int row = idx / 80;
    int col = idx - row * 80;
    p2s[row * 82 + col] = f2bf(ws[WS_P2 + j0 * 80 + idx]);
  }

  // GEMM1 B-frags: B[k=c][n=k_out] = bf16(W_h2[n][64+c])
  bf16x8 wb[5];
#pragma unroll
  for (int t = 0; t < 5; t++) {
    int n = t * 16 + c16;
    const float* src = W_h2 + n * 160 + 64 + q * 8;
    u16x8 u;
#pragma unroll
    for (int jj = 0; jj < 8; jj++) u[jj] = f2bf(src[jj]);
    wb[t] = __builtin_bit_cast(bf16x8, u);
  }
  // GEMM1 A-frag: A[m=edge][k=c] = bf16(edge_attr)
  int mA = i * 512 + j0 + wave * 16 + c16;
  bf16x8 af;
  {
    const float* src = ea + mA * 32 + q * 8;
    u16x8 u;
#pragma unroll
    for (int jj = 0; jj < 8; jj++) u[jj] = f2bf(src[jj]);
    af = __builtin_bit_cast(bf16x8, u);
  }

  __syncthreads();  // P1/P2 staging visible

  // acc init = P1b[i][n] + P2[j][n]  (rows = edges q*4+r, col n = t*16+c16)
  f32x4 acc[5];
#pragma unroll
  for (int t = 0; t < 5; t++) {
    int n = t * 16 + c16;
    float p1v = p1s[n];
#pragma unroll
    for (int r = 0; r < 4; r++) {
      int jl = wave * 16 + q * 4 + r;
      acc[t][r] = p1v + bf2f(p2s[jl * 82 + n]);
    }
  }
#pragma unroll
  for (int t = 0; t < 5; t++)
    acc[t] = __builtin_amdgcn_mfma_f32_16x16x32_bf16(af, wb[t], acc[t], 0, 0, 0);

  // lrelu -> ht (bf16); each wave writes only its own 16-row stripe
#pragma unroll
  for (int t = 0; t < 5; t++)
#pragma unroll
    for (int r = 0; r < 4; r++)
      ht[(wave * 16 + q * 4 + r) * 104 + t * 16 + c16] = f2bf(lrelu(acc[t][r]));

  // GEMM2 B-frags: B[k][n=c_out] = bf16(W_eo[c_out][k]), zero-padded past k=80
  bf16x8 wo[2][3];
#pragma unroll
  for (int t2 = 0; t2 < 2; t2++)
#pragma unroll
    for (int s = 0; s < 3; s++) {
      int kk = s * 32 + q * 8;
      u16x8 u = {0, 0, 0, 0, 0, 0, 0, 0};
      if (kk < 80) {
        const float* src = W_eo + (t2 * 16 + c16) * 80 + kk;
#pragma unroll
        for (int jj = 0; jj < 8; jj++) u[jj] = f2bf(src[jj]);
      }
      wo[t2][s] = __builtin_bit_cast(bf16x8, u);
    }

  // GEMM2: ne = h @ W_eo^T ; A re-read from ht (same-wave stripe, A-operand layout)
  f32x4 z4 = {0.f, 0.f, 0.f, 0.f};
  f32x4 acc2[2] = {z4, z4};
  int hrow = wave * 16 + c16;
#pragma unroll
  for (int s = 0; s < 3; s++) {
    int kk = s * 32 + q * 8;
    u16x8 hbits = {0, 0, 0, 0, 0, 0, 0, 0};
    if (kk < 80) hbits = *(const u16x8*)&ht[hrow * 104 + kk];
    bf16x8 ha = __builtin_bit_cast(bf16x8, hbits);
#pragma unroll
    for (int t2 = 0; t2 < 2; t2++)
      acc2[t2] = __builtin_amdgcn_mfma_f32_16x16x32_bf16(ha, wo[t2][s], acc2[t2], 0, 0, 0);
  }

  // epilogue: bias, lrelu, mask; store fp32; col stats; score contributions
  float beo[2] = {b_eo[c16], b_eo[16 + c16]};
  float eve[2] = {ev[64 + c16], ev[80 + c16]};
  float ne[2][4];
  float scs[2] = {0.f, 0.f}, scss[2] = {0.f, 0.f};
#pragma unroll
  for (int t2 = 0; t2 < 2; t2++)
#pragma unroll
    for (int r = 0; r < 4; r++) {
      int m = i * 512 + j0 + wave * 16 + q * 4 + r;
      float mf = mask[m] ? 1.f : 0.f;
      float v = lrelu(acc2[t2][r] + beo[t2]) * mf;
      ne[t2][r] = v;
      scs[t2] += v;
      scss[t2] += v * v;
      out_e[m * 32 + t2 * 16 + c16] = v;
    }
  // per-wave column stats: reduce over q (lane bits 4,5)
#pragma unroll
  for (int t2 = 0; t2 < 2; t2++) {
    float a_ = scs[t2], b_ = scss[t2];
    a_ += __shfl_xor(a_, 16, 64); a_ += __shfl_xor(a_, 32, 64);
    b_ += __shfl_xor(b_, 16, 64); b_ += __shfl_xor(b_, 32, 64);
    if (q == 0) {
      wred[0][wave][t2 * 16 + c16] = a_;
      wred[1][wave][t2 * 16 + c16] = b_;
    }
  }
  // scores: se[r] = dot(ne[row], ev_mid), reduced over c16 (lane bits 0..3)
  float se[4];
#pragma unroll
  for (int r = 0; r < 4; r++) {
    float s = ne[0][r] * eve[0] + ne[1][r] * eve[1];
#pragma unroll
    for (int off = 8; off >= 1; off >>= 1) s += __shfl_xor(s, off, 64);
    se[r] = s;
  }
  if (c16 < 4) {
    float s = (c16 == 0) ? se[0] : (c16 == 1) ? se[1] : (c16 == 2) ? se[2] : se[3];
    int j = j0 + wave * 16 + q * 4 + c16;
    ws[WS_SC + i * 512 + j] = lrelu(ws[WS_A + i] + ws[WS_B + j] + s);
  }
  __syncthreads();
  // striped partial-stat accumulation: slot = blk>>3 (8-way contention only)
  if (tid < 64) {
    int half = tid >> 5;  // 0=sum, 1=sumsq
    int col = tid & 31;
    float v = wred[half][0][col] + wred[half][1][col] + wred[half][2][col] +
              wred[half][3][col];
    atomicAdd(&part[(blk >> 3) * 64 + tid], v);
  }
}

// ---------------- K3: row softmax + mask + att@xn (pre-BN new_x) ----------------
__global__ void __launch_bounds__(512) k3(const int* __restrict__ mask, float* ws) {
  __shared__ float att[512];
  __shared__ float red[8];
  __shared__ float nx[8][64];
  int i = blockIdx.x, tid = threadIdx.x;
  int wave = tid >> 6, lane = tid & 63;
  // scores bounded (|s| < ~12), so exp without max-subtraction is fp32-safe;
  // softmax is shift-invariant so result matches the reference.
  float p = __expf(ws[WS_SC + i * 512 + tid]);
  float sm = p;
#pragma unroll
  for (int off = 32; off >= 1; off >>= 1) sm += __shfl_xor(sm, off, 64);
  if (lane == 0) red[wave] = sm;
  __syncthreads();
  float tot = red[0] + red[1] + red[2] + red[3] + red[4] + red[5] + red[6] + red[7];
  att[tid] = p * (1.f / tot) * (mask[i * 512 + tid] ? 1.f : 0.f);
  __syncthreads();
  // new_x[i][c] = sum_j att[j]*xn[j][c]; wave w covers j in [w*64, (w+1)*64)
  int c = lane;
  const float* xn = ws + WS_XN;
  float accv = 0.f;
#pragma unroll 4
  for (int u = 0; u < 64; u++) {
    int j = wave * 64 + u;
    accv += att[j] * xn[j * 64 + c];
  }
  nx[wave][c] = accv;
  __syncthreads();
  if (tid < 64) {
    float s = 0.f;
#pragma unroll
    for (int w = 0; w < 8; w++) s += nx[w][tid];
    ws[WS_NEWX + i * 64 + tid] = s;
  }
}

// ---------------- K4: blk0 = node BN stats; blk1 = reduce edge stat partials ----------------
__global__ void __launch_bounds__(256) k4(const float* __restrict__ bn_n_w,
                                          const float* __restrict__ bn_n_b,
                                          const float* __restrict__ part,
                                          float* ws) {
  __shared__ float s1[4][64], s2[4][64];
  int tid = threadIdx.x;
  int c = tid & 63, g = tid >> 6;
  if (blockIdx.x == 0) {
    float a = 0.f, b = 0.f;
#pragma unroll 4
    for (int u = 0; u < 128; u++) {
      float v = ws[WS_NEWX + (g * 128 + u) * 64 + c];
      a += v;
      b += v * v;
    }
    s1[g][c] = a;
    s2[g][c] = b;
    __syncthreads();
    if (tid < 64) {
      float sum = s1[0][tid] + s1[1][tid] + s1[2][tid] + s1[3][tid];
      float ssq = s2[0][tid] + s2[1][tid] + s2[2][tid] + s2[3][tid];
      float mean = sum * (1.f / 512.f);
      float var = ssq * (1.f / 512.f) - mean * mean;
      float scl = bn_n_w[tid] * rsqrtf(fmaxf(var, 0.f) + EPS);
      ws[WS_NSCALE + tid] = scl;
      ws[WS_NSHIFT + tid] = bn_n_b[tid] - mean * scl;
    }
  } else {
    // reduce 512 slots x 64 cols of edge partials -> ESUM[0:32] / ESQ[0:32]
    float a = 0.f;
    for (int s = g; s < 512; s += 4) a += part[s * 64 + c];
    s1[g][c] = a;
    __syncthreads();
    if (tid < 64)
      ws[WS_ESUM + tid] = s1[0][tid] + s1[1][tid] + s1[2][tid] + s1[3][tid];
  }
}

// ---------------- K5: apply BN to new_x (blocks 0..7) and edges (blocks 8..4103) ----------------
__global__ void __launch_bounds__(256) k5(const float* __restrict__ bn_e_w,
                                          const float* __restrict__ bn_e_b,
                                          const float* __restrict__ ws,
                                          float* __restrict__ out) {
  __shared__ float esc[32], esh[32];
  int blk = blockIdx.x, tid = threadIdx.x;
  if (blk < 8) {
#pragma unroll 4
    for (int u = 0; u < 16; u++) {
      int idx = blk * 4096 + u * 256 + tid;
      int c = idx & 63;
      out[idx] = ws[WS_NEWX + idx] * ws[WS_NSCALE + c] + ws[WS_NSHIFT + c];
    }
  } else {
    if (tid < 32) {
      float mean = ws[WS_ESUM + tid] * (1.f / 262144.f);
      float var = ws[WS_ESQ + tid] * (1.f / 262144.f) - mean * mean;
      float s = bn_e_w[tid] * rsqrtf(fmaxf(var, 0.f) + EPS);
      esc[tid] = s;
      esh[tid] = bn_e_b[tid] - mean * s;
    }
    __syncthreads();
    float* oe = out + 32768;
    int base = ((blk - 8) * 256 + tid) * 8;  // 8 floats per thread, 32B aligned
    f32x4 r0 = *(const f32x4*)(oe + base);
    f32x4 r1 = *(const f32x4*)(oe + base + 4);
    int c0 = base & 31;
    f32x4 w0, w1;
#pragma unroll
    for (int u = 0; u < 4; u++) {
      w0[u] = r0[u] * esc[c0 + u] + esh[c0 + u];
      w1[u] = r1[u] * esc[c0 + 4 + u] + esh[c0 + 4 + u];
    }
    *(f32x4*)(oe + base) = w0;
    *(f32x4*)(oe + base + 4) = w1;
  }
}

extern "C" void kernel_launch(void* const* d_in, const int* in_sizes, int n_in,
                              void* d_out, int out_size, void* d_ws, size_t ws_size,
                              hipStream_t stream) {
  const float* x = (const float*)d_in[0];
  const float* ea = (const float*)d_in[1];
  const int* mask = (const int*)d_in[2];
  const float* Wnu = (const float*)d_in[3];
  const float* bnu = (const float*)d_in[4];
  const float* Wh2 = (const float*)d_in[5];
  const float* bh2 = (const float*)d_in[6];
  const float* Weo = (const float*)d_in[7];
  const float* beo = (const float*)d_in[8];
  const float* ev = (const float*)d_in[9];
  const float* bnw = (const float*)d_in[10];
  const float* bnb = (const float*)d_in[11];
  const float* bew = (const float*)d_in[12];
  const float* beb = (const float*)d_in[13];
  float* ws = (float*)d_ws;
  float* out = (float*)d_out;
  float* part = out;  // 512 slots x 64 f32 = out[0:32768] (x-region, dead until k5)

  hipMemsetAsync(part, 0, 512 * 64 * sizeof(float), stream);
  k1<<<448, 256, 0, stream>>>(x, Wnu, bnu, Wh2, bh2, ev, ws);
  k2<<<4096, 256, 0, stream>>>(ea, mask, Wh2, Weo, beo, ev, ws, part, out + 32768);
  k3<<<512, 512, 0, stream>>>(mask, ws);
  k4<<<2, 256, 0, stream>>>(bnw, bnb, part, ws);
  k5<<<4104, 256, 0, stream>>>(bew, beb, ws, out);
}

// Round 5
// 167.648 us; speedup vs baseline: 1.4878x; 1.1836x over previous
//
#include <hip/hip_runtime.h>

#define SLOPE 0.1f
#define EPS 1e-5f

typedef __bf16 bf16x8 __attribute__((ext_vector_type(8)));
typedef unsigned short u16x8 __attribute__((ext_vector_type(8)));
typedef float f32x4 __attribute__((ext_vector_type(4)));

// ---- workspace layout ----
// float offsets on (float*)ws:
#define WS_ESUM 0       // 32  edge col sums   (written by k3 blk 512)
#define WS_ESQ 32       // 32  edge col sumsq
#define WS_A 192        // 512 : dot(xn_i, ev[0:64])
#define WS_B 704        // 512 : dot(xn_j, ev[96:160])
#define WS_XN 1216      // 512*64 post-lrelu node feats
#define WS_NEWX 33984   // 512*64 pre-BN new_x
#define WS_P1B 66752    // 512*80 : b_h2[k] + x_i . W_h2[k][0:64]
#define WS_P2 107712    // 512*80 : x_j . W_h2[k][96:160]
#define WS_SC 148672    // 512*512 scores (post-lrelu, pre-softmax)
// u16 offsets on (unsigned short*)ws (bf16 payloads), after float end 410816:
#define WSH_WB 821632   // 80*64  bf16 W_h2[n][64+c]      (GEMM1 B)
#define WSH_WO 826752   // 32*96  bf16 W_eo[n][k], 0-pad  (GEMM2 B)
// total ws = 829824 u16 = 1.66 MB
// edge-BN partials: 512 slots x 64 f32 in d_out[0:32768] (x-region, dead till k5);
// zeroed by k1 blocks 0..127, atomically accumulated by k2, reduced by k3 blk 512.

__device__ __forceinline__ float lrelu(float v) { return v > 0.f ? v : SLOPE * v; }
__device__ __forceinline__ unsigned short f2bf(float f) {
  unsigned x = __float_as_uint(f);
  return (unsigned short)((x + 0x7fffu + ((x >> 16) & 1u)) >> 16);
}

// ---------------- K1 ----------------
// blocks 0..127 : xn + a/b scalars, zero part, build bf16 weight copies
// blocks 128..207 : P1/P2 via MFMA  (M=512 x N=160, K=64)
__global__ void __launch_bounds__(256) k1(const float* __restrict__ x,
                                          const float* __restrict__ W_nu,
                                          const float* __restrict__ b_nu,
                                          const float* __restrict__ W_h2,
                                          const float* __restrict__ b_h2,
                                          const float* __restrict__ W_eo,
                                          const float* __restrict__ ev,
                                          float* ws, float* __restrict__ part) {
  int blk = blockIdx.x;
  int tid = threadIdx.x;
  unsigned short* wsh = (unsigned short*)ws;
  if (blk < 128) {
    __shared__ float wlds[64 * 65];
#pragma unroll
    for (int it = 0; it < 16; it++) {
      int idx = it * 256 + tid;
      wlds[(idx >> 6) * 65 + (idx & 63)] = W_nu[idx];
    }
    int gid = blk * 256 + tid;  // 0..32767
    part[gid] = 0.f;
    if (gid < 5120) {
      wsh[WSH_WB + gid] = f2bf(W_h2[(gid >> 6) * 160 + 64 + (gid & 63)]);
    } else if (gid < 8192) {
      int idx = gid - 5120;
      int n = idx / 96, kk = idx - 96 * n;
      wsh[WSH_WO + idx] = (kk < 80) ? f2bf(W_eo[n * 80 + kk]) : (unsigned short)0;
    }
    __syncthreads();
    int i = blk * 4 + (tid >> 6);
    int c = tid & 63;
    float acc = b_nu[c];
    const float* xr = x + i * 64;
#pragma unroll 8
    for (int k = 0; k < 64; k++) acc += xr[k] * wlds[c * 65 + k];
    float xnv = lrelu(acc);
    ws[WS_XN + i * 64 + c] = xnv;
    float va = xnv * ev[c];
    float vb = xnv * ev[96 + c];
#pragma unroll
    for (int off = 32; off >= 1; off >>= 1) {
      va += __shfl_xor(va, off, 64);
      vb += __shfl_xor(vb, off, 64);
    }
    if (c == 0) { ws[WS_A + i] = va; ws[WS_B + i] = vb; }
  } else {
    // MFMA P-GEMM: block b2 covers 64 rows (bm) x 16 cols (bn) of N=160
    int b2 = blk - 128;          // 0..79
    int bm = b2 & 7, bn = b2 >> 3;  // bm: M-tile of 64, bn: N-tile of 16
    int wave = tid >> 6, lane = tid & 63;
    int c16 = lane & 15, q = lane >> 4;
    int n = bn * 16 + c16;       // 0..159
    const float* wrow = (n < 80) ? (W_h2 + n * 160) : (W_h2 + (n - 80) * 160 + 96);
    int mrow = bm * 64 + wave * 16 + c16;
    bf16x8 bf[2], af[2];
#pragma unroll
    for (int ks = 0; ks < 2; ks++) {
      const float* bs = wrow + ks * 32 + q * 8;
      const float* as = x + mrow * 64 + ks * 32 + q * 8;
      u16x8 ub, ua;
#pragma unroll
      for (int jj = 0; jj < 8; jj++) { ub[jj] = f2bf(bs[jj]); ua[jj] = f2bf(as[jj]); }
      bf[ks] = __builtin_bit_cast(bf16x8, ub);
      af[ks] = __builtin_bit_cast(bf16x8, ua);
    }
    float bias = (n < 80) ? b_h2[n] : 0.f;
    f32x4 acc = {bias, bias, bias, bias};
    acc = __builtin_amdgcn_mfma_f32_16x16x32_bf16(af[0], bf[0], acc, 0, 0, 0);
    acc = __builtin_amdgcn_mfma_f32_16x16x32_bf16(af[1], bf[1], acc, 0, 0, 0);
#pragma unroll
    for (int r = 0; r < 4; r++) {
      int mm = bm * 64 + wave * 16 + q * 4 + r;
      if (n < 80) ws[WS_P1B + mm * 80 + n] = acc[r];
      else        ws[WS_P2 + mm * 80 + (n - 80)] = acc[r];
    }
  }
}

// ---------------- K2: fused edge MLP (MFMA) + scores + BN-stat partials ----------------
// block = 64 edges (one i, 64 consecutive j), 4 waves x 16 edges each
__global__ void __launch_bounds__(256) k2(const float* __restrict__ ea,
                                          const int* __restrict__ mask,
                                          const float* __restrict__ b_eo,
                                          const float* __restrict__ ev,
                                          float* ws,
                                          float* __restrict__ part,   // 512 slots x 64
                                          float* __restrict__ out_e) {
  __shared__ unsigned short ht[64 * 104];  // h tile bf16 (rows stride 104 u16)
  __shared__ float wred[2][4][32];         // [sum|sumsq][wave][col]
  int tid = threadIdx.x;
  int wave = tid >> 6, lane = tid & 63;
  int c16 = lane & 15, q = lane >> 4;
  int blk = blockIdx.x;
  int i = blk >> 3, j0 = (blk & 7) << 6;
  const unsigned short* wsh = (const unsigned short*)ws;

  // GEMM1 B-frags: direct bf16 loads
  bf16x8 wb[5];
#pragma unroll
  for (int t = 0; t < 5; t++)
    wb[t] = __builtin_bit_cast(
        bf16x8, *(const u16x8*)(wsh + WSH_WB + (t * 16 + c16) * 64 + q * 8));
  // GEMM1 A-frag: bf16(edge_attr)
  int mA = i * 512 + j0 + wave * 16 + c16;
  bf16x8 af;
  {
    const float* src = ea + mA * 32 + q * 8;
    u16x8 u;
#pragma unroll
    for (int jj = 0; jj < 8; jj++) u[jj] = f2bf(src[jj]);
    af = __builtin_bit_cast(bf16x8, u);
  }

  // acc init = P1b[i][n] + P2[j][n]  (rows = edges q*4+r, col n = t*16+c16)
  f32x4 acc[5];
#pragma unroll
  for (int t = 0; t < 5; t++) {
    int n = t * 16 + c16;
    float p1v = ws[WS_P1B + i * 80 + n];
#pragma unroll
    for (int r = 0; r < 4; r++) {
      int j = j0 + wave * 16 + q * 4 + r;
      acc[t][r] = p1v + ws[WS_P2 + j * 80 + n];
    }
  }
#pragma unroll
  for (int t = 0; t < 5; t++)
    acc[t] = __builtin_amdgcn_mfma_f32_16x16x32_bf16(af, wb[t], acc[t], 0, 0, 0);

  // lrelu -> ht (bf16); wave-local stripe, no barrier needed
#pragma unroll
  for (int t = 0; t < 5; t++)
#pragma unroll
    for (int r = 0; r < 4; r++)
      ht[(wave * 16 + q * 4 + r) * 104 + t * 16 + c16] = f2bf(lrelu(acc[t][r]));

  // GEMM2 B-frags: direct bf16 loads (pre-padded to 96)
  bf16x8 wo[2][3];
#pragma unroll
  for (int t2 = 0; t2 < 2; t2++)
#pragma unroll
    for (int s = 0; s < 3; s++)
      wo[t2][s] = __builtin_bit_cast(
          bf16x8,
          *(const u16x8*)(wsh + WSH_WO + (t2 * 16 + c16) * 96 + s * 32 + q * 8));

  // GEMM2: ne = h @ W_eo^T ; A from ht (same-wave stripe, A-operand layout)
  f32x4 z4 = {0.f, 0.f, 0.f, 0.f};
  f32x4 acc2[2] = {z4, z4};
  int hrow = wave * 16 + c16;
#pragma unroll
  for (int s = 0; s < 3; s++) {
    int kk = s * 32 + q * 8;
    u16x8 hbits = {0, 0, 0, 0, 0, 0, 0, 0};
    if (kk < 80) hbits = *(const u16x8*)&ht[hrow * 104 + kk];
    bf16x8 ha = __builtin_bit_cast(bf16x8, hbits);
#pragma unroll
    for (int t2 = 0; t2 < 2; t2++)
      acc2[t2] = __builtin_amdgcn_mfma_f32_16x16x32_bf16(ha, wo[t2][s], acc2[t2], 0, 0, 0);
  }

  // epilogue: bias, lrelu, mask; store fp32; col stats; score contributions
  float beo[2] = {b_eo[c16], b_eo[16 + c16]};
  float eve[2] = {ev[64 + c16], ev[80 + c16]};
  float ne[2][4];
  float scs[2] = {0.f, 0.f}, scss[2] = {0.f, 0.f};
#pragma unroll
  for (int t2 = 0; t2 < 2; t2++)
#pragma unroll
    for (int r = 0; r < 4; r++) {
      int m = i * 512 + j0 + wave * 16 + q * 4 + r;
      float mf = mask[m] ? 1.f : 0.f;
      float v = lrelu(acc2[t2][r] + beo[t2]) * mf;
      ne[t2][r] = v;
      scs[t2] += v;
      scss[t2] += v * v;
      out_e[m * 32 + t2 * 16 + c16] = v;
    }
  // per-wave column stats: reduce over q (lane bits 4,5)
#pragma unroll
  for (int t2 = 0; t2 < 2; t2++) {
    float a_ = scs[t2], b_ = scss[t2];
    a_ += __shfl_xor(a_, 16, 64); a_ += __shfl_xor(a_, 32, 64);
    b_ += __shfl_xor(b_, 16, 64); b_ += __shfl_xor(b_, 32, 64);
    if (q == 0) {
      wred[0][wave][t2 * 16 + c16] = a_;
      wred[1][wave][t2 * 16 + c16] = b_;
    }
  }
  // scores: se[r] = dot(ne[row], ev_mid), reduced over c16 (lane bits 0..3)
  float se[4];
#pragma unroll
  for (int r = 0; r < 4; r++) {
    float s = ne[0][r] * eve[0] + ne[1][r] * eve[1];
#pragma unroll
    for (int off = 8; off >= 1; off >>= 1) s += __shfl_xor(s, off, 64);
    se[r] = s;
  }
  if (c16 < 4) {
    float s = (c16 == 0) ? se[0] : (c16 == 1) ? se[1] : (c16 == 2) ? se[2] : se[3];
    int j = j0 + wave * 16 + q * 4 + c16;
    ws[WS_SC + i * 512 + j] = lrelu(ws[WS_A + i] + ws[WS_B + j] + s);
  }
  __syncthreads();
  // striped partial-stat accumulation: slot = blk>>3 (8-way contention)
  if (tid < 64) {
    int half = tid >> 5;
    int col = tid & 31;
    float v = wred[half][0][col] + wred[half][1][col] + wred[half][2][col] +
              wred[half][3][col];
    atomicAdd(&part[(blk >> 3) * 64 + tid], v);
  }
}

// ---------------- K3: softmax+att@xn (blocks 0..511); blk 512 reduces edge partials ----------------
__global__ void __launch_bounds__(512) k3(const int* __restrict__ mask,
                                          const float* __restrict__ part,
                                          float* ws) {
  __shared__ float att[512];
  __shared__ float red[8];
  __shared__ float nx[8][64];
  int i = blockIdx.x, tid = threadIdx.x;
  int wave = tid >> 6, lane = tid & 63;
  if (i == 512) {
    // reduce 512 slots x 64 cols -> ESUM[0:32] / ESQ[0:32]
    int c = tid & 63, g = tid >> 6;
    float a = 0.f;
    for (int s = g; s < 512; s += 8) a += part[s * 64 + c];
    nx[g][c] = a;
    __syncthreads();
    if (tid < 64) {
      float t = 0.f;
#pragma unroll
      for (int g2 = 0; g2 < 8; g2++) t += nx[g2][tid];
      ws[WS_ESUM + tid] = t;  // ESQ adjacent
    }
    return;
  }
  // scores bounded small -> exp without max-subtraction is fp32-safe (shift-invariant)
  float p = __expf(ws[WS_SC + i * 512 + tid]);
  float sm = p;
#pragma unroll
  for (int off = 32; off >= 1; off >>= 1) sm += __shfl_xor(sm, off, 64);
  if (lane == 0) red[wave] = sm;
  __syncthreads();
  float tot = red[0] + red[1] + red[2] + red[3] + red[4] + red[5] + red[6] + red[7];
  att[tid] = p * (1.f / tot) * (mask[i * 512 + tid] ? 1.f : 0.f);
  __syncthreads();
  int c = lane;
  const float* xn = ws + WS_XN;
  float accv = 0.f;
#pragma unroll 4
  for (int u = 0; u < 64; u++) {
    int j = wave * 64 + u;
    accv += att[j] * xn[j * 64 + c];
  }
  nx[wave][c] = accv;
  __syncthreads();
  if (tid < 64) {
    float s = 0.f;
#pragma unroll
    for (int w = 0; w < 8; w++) s += nx[w][tid];
    ws[WS_NEWX + i * 64 + tid] = s;
  }
}

// ---------------- K5: blocks 0..7 node BN (stats redundant per block) + apply;
//                     blocks 8..4103 edge BN apply ----------------
__global__ void __launch_bounds__(256) k5(const float* __restrict__ bn_n_w,
                                          const float* __restrict__ bn_n_b,
                                          const float* __restrict__ bn_e_w,
                                          const float* __restrict__ bn_e_b,
                                          const float* __restrict__ ws,
                                          float* __restrict__ out) {
  int blk = blockIdx.x, tid = threadIdx.x;
  if (blk < 8) {
    __shared__ float s1[4][64], s2[4][64], scl[64], sh[64];
    int c = tid & 63, g = tid >> 6;
    float a = 0.f, b = 0.f;
#pragma unroll 4
    for (int u = 0; u < 128; u++) {
      float v = ws[WS_NEWX + (g * 128 + u) * 64 + c];
      a += v;
      b += v * v;
    }
    s1[g][c] = a;
    s2[g][c] = b;
    __syncthreads();
    if (tid < 64) {
      float sum = s1[0][tid] + s1[1][tid] + s1[2][tid] + s1[3][tid];
      float ssq = s2[0][tid] + s2[1][tid] + s2[2][tid] + s2[3][tid];
      float mean = sum * (1.f / 512.f);
      float var = ssq * (1.f / 512.f) - mean * mean;
      float s = bn_n_w[tid] * rsqrtf(fmaxf(var, 0.f) + EPS);
      scl[tid] = s;
      sh[tid] = bn_n_b[tid] - mean * s;
    }
    __syncthreads();
#pragma unroll 4
    for (int u = 0; u < 16; u++) {
      int idx = blk * 4096 + u * 256 + tid;
      int c2 = idx & 63;
      out[idx] = ws[WS_NEWX + idx] * scl[c2] + sh[c2];
    }
  } else {
    __shared__ float esc[32], esh[32];
    if (tid < 32) {
      float mean = ws[WS_ESUM + tid] * (1.f / 262144.f);
      float var = ws[WS_ESQ + tid] * (1.f / 262144.f) - mean * mean;
      float s = bn_e_w[tid] * rsqrtf(fmaxf(var, 0.f) + EPS);
      esc[tid] = s;
      esh[tid] = bn_e_b[tid] - mean * s;
    }
    __syncthreads();
    float* oe = out + 32768;
    int base = ((blk - 8) * 256 + tid) * 8;
    f32x4 r0 = *(const f32x4*)(oe + base);
    f32x4 r1 = *(const f32x4*)(oe + base + 4);
    int c0 = base & 31;
    f32x4 w0, w1;
#pragma unroll
    for (int u = 0; u < 4; u++) {
      w0[u] = r0[u] * esc[c0 + u] + esh[c0 + u];
      w1[u] = r1[u] * esc[c0 + 4 + u] + esh[c0 + 4 + u];
    }
    *(f32x4*)(oe + base) = w0;
    *(f32x4*)(oe + base + 4) = w1;
  }
}

extern "C" void kernel_launch(void* const* d_in, const int* in_sizes, int n_in,
                              void* d_out, int out_size, void* d_ws, size_t ws_size,
                              hipStream_t stream) {
  const float* x = (const float*)d_in[0];
  const float* ea = (const float*)d_in[1];
  const int* mask = (const int*)d_in[2];
  const float* Wnu = (const float*)d_in[3];
  const float* bnu = (const float*)d_in[4];
  const float* Wh2 = (const float*)d_in[5];
  const float* bh2 = (const float*)d_in[6];
  const float* Weo = (const float*)d_in[7];
  const float* beo = (const float*)d_in[8];
  const float* ev = (const float*)d_in[9];
  const float* bnw = (const float*)d_in[10];
  const float* bnb = (const float*)d_in[11];
  const float* bew = (const float*)d_in[12];
  const float* beb = (const float*)d_in[13];
  float* ws = (float*)d_ws;
  float* out = (float*)d_out;
  float* part = out;  // 512 x 64 f32 partials in x-region (dead until k5)

  k1<<<208, 256, 0, stream>>>(x, Wnu, bnu, Wh2, bh2, Weo, ev, ws, part);
  k2<<<4096, 256, 0, stream>>>(ea, mask, beo, ev, ws, part, out + 32768);
  k3<<<513, 512, 0, stream>>>(mask, part, ws);
  k5<<<4104, 256, 0, stream>>>(bnw, bnb, bew, beb, ws, out);
}